// Round 6
// baseline (305.231 us; speedup 1.0000x reference)
//
#include <hip/hip_runtime.h>
#include <hip/hip_bf16.h>
#include <math.h>

typedef float f32x4 __attribute__((ext_vector_type(4)));
typedef int   i32x4 __attribute__((ext_vector_type(4)));
typedef int   i32x8 __attribute__((ext_vector_type(8)));

#define BSZ 8192
#define DIM 2048
#define NTILE 64          // 8192 / 128 tiles per side
#define BK 128            // K elements per step (one MX mfma)
#define KSTEPS 16         // 2048 / 128

// MX e8m0 scale byte for 2^-4 (we pre-scale inputs by 16): 127-4 = 123.
#define SCALE_I32 0x7B7B7B7B

// ---------- kernel 1: fused normalize -> fp8(x*16), diag cos (fp32) ----------
__global__ void __launch_bounds__(256) k_prep(const float* __restrict__ X,
                                              const float* __restrict__ Y,
                                              unsigned char* __restrict__ Xq,
                                              unsigned char* __restrict__ Yq,
                                              float* __restrict__ dg) {
  const int row = blockIdx.x;
  const int tid = threadIdx.x;
  const float4* xp = (const float4*)(X + (size_t)row * DIM);
  const float4* yp = (const float4*)(Y + (size_t)row * DIM);
  float4 x0 = xp[tid * 2], x1 = xp[tid * 2 + 1];
  float4 y0 = yp[tid * 2], y1 = yp[tid * 2 + 1];
  float sxx = x0.x*x0.x + x0.y*x0.y + x0.z*x0.z + x0.w*x0.w
            + x1.x*x1.x + x1.y*x1.y + x1.z*x1.z + x1.w*x1.w;
  float syy = y0.x*y0.x + y0.y*y0.y + y0.z*y0.z + y0.w*y0.w
            + y1.x*y1.x + y1.y*y1.y + y1.z*y1.z + y1.w*y1.w;
  float sxy = x0.x*y0.x + x0.y*y0.y + x0.z*y0.z + x0.w*y0.w
            + x1.x*y1.x + x1.y*y1.y + x1.z*y1.z + x1.w*y1.w;
#pragma unroll
  for (int m = 32; m >= 1; m >>= 1) {
    sxx += __shfl_xor(sxx, m);
    syy += __shfl_xor(syy, m);
    sxy += __shfl_xor(sxy, m);
  }
  __shared__ float sh[3][4];
  if ((tid & 63) == 0) {
    sh[0][tid >> 6] = sxx; sh[1][tid >> 6] = syy; sh[2][tid >> 6] = sxy;
  }
  __syncthreads();
  float xx = sh[0][0] + sh[0][1] + sh[0][2] + sh[0][3];
  float yy = sh[1][0] + sh[1][1] + sh[1][2] + sh[1][3];
  float xy = sh[2][0] + sh[2][1] + sh[2][2] + sh[2][3];
  float nx = fmaxf(sqrtf(xx), 1e-8f);
  float ny = fmaxf(sqrtf(yy), 1e-8f);
  float ix = 16.0f / nx, iy = 16.0f / ny;   // x16 pre-scale into e4m3 sweet spot
  float vx[8] = {x0.x, x0.y, x0.z, x0.w, x1.x, x1.y, x1.z, x1.w};
  float vy[8] = {y0.x, y0.y, y0.z, y0.w, y1.x, y1.y, y1.z, y1.w};
  int px0 = __builtin_amdgcn_cvt_pk_fp8_f32(vx[0]*ix, vx[1]*ix, 0, false);
  px0     = __builtin_amdgcn_cvt_pk_fp8_f32(vx[2]*ix, vx[3]*ix, px0, true);
  int px1 = __builtin_amdgcn_cvt_pk_fp8_f32(vx[4]*ix, vx[5]*ix, 0, false);
  px1     = __builtin_amdgcn_cvt_pk_fp8_f32(vx[6]*ix, vx[7]*ix, px1, true);
  int py0 = __builtin_amdgcn_cvt_pk_fp8_f32(vy[0]*iy, vy[1]*iy, 0, false);
  py0     = __builtin_amdgcn_cvt_pk_fp8_f32(vy[2]*iy, vy[3]*iy, py0, true);
  int py1 = __builtin_amdgcn_cvt_pk_fp8_f32(vy[4]*iy, vy[5]*iy, 0, false);
  py1     = __builtin_amdgcn_cvt_pk_fp8_f32(vy[6]*iy, vy[7]*iy, py1, true);
  int2 ox; ox.x = px0; ox.y = px1;
  int2 oy; oy.x = py0; oy.y = py1;
  *(int2*)(Xq + (size_t)row * DIM + tid * 8) = ox;
  *(int2*)(Yq + (size_t)row * DIM + tid * 8) = oy;
  if (tid == 0) dg[row] = xy / (nx * ny);
}

// ---------- kernel 2: 128x128-tile MX-fp8 GEMM ----------
// A operand: DIRECT global -> registers (perfectly coalesced: a wave's 64
// lanes cover 16 full 128-B rows per load), one-iteration register prefetch.
// B operand: double-buffered LDS (2 x 16 KiB), global_load_lds w=16, XOR-8
// swizzle via pre-swizzled global source (rule #21).
// ONE barrier per K-step: STAGE_B(t+1) overwrites the buffer last read at
// t-1, whose reads completed before the end-of-(t-1) barrier -> WAR safe.
// Natural block raster (round-5 XCD swizzle reverted: FETCH 92->532 MB).
__global__ void __launch_bounds__(256) k_gemm(const unsigned char* __restrict__ Xq,
                                              const unsigned char* __restrict__ Yq,
                                              float* __restrict__ rowpart,
                                              float* __restrict__ colpart) {
  const int bm = blockIdx.x & (NTILE - 1);
  const int bn = blockIdx.x >> 6;
  const int tileRow = bm * 128;
  const int tileCol = bn * 128;

  __shared__ __align__(16) unsigned char Bs[2][128][BK];   // 32 KiB
  __shared__ float rsum2[2][128];
  __shared__ float csum2[2][128];

  const int tid = threadIdx.x;
  const int lane = tid & 63;
  const int w = tid >> 6;        // wave 0..3
  const int wr = w >> 1;         // wave row 0..1  (64-row sub-tile)
  const int wc = w & 1;          // wave col 0..1  (64-col sub-tile)
  const int lo = lane & 15;
  const int hi = lane >> 4;      // k-quarter 0..3

  f32x4 acc[4][4];
#pragma unroll
  for (int m = 0; m < 4; ++m)
#pragma unroll
    for (int n = 0; n < 4; ++n) acc[m][n] = (f32x4){0.f, 0.f, 0.f, 0.f};

  // ---- B staging source (swizzled): wave w covers rows [w*32, w*32+32) ----
  // lane l: row +(l>>3), physical chunk l&7 <- logical chunk (l&7)^(l>>3).
  const size_t lrow = (size_t)(lane >> 3);
  const int    lcol = (((lane & 7) ^ (lane >> 3)) * 16);
  const unsigned char* gyb = Yq + ((size_t)(tileCol + w * 32) + lrow) * DIM + lcol;

  // ---- A direct per-lane base pointers: lane (lo,hi) reads row
  // tileRow + wr*64 + m*16 + lo, bytes [t*128 + hi*32, +32) ----
  const unsigned char* ga0 = Xq + (size_t)(tileRow + wr * 64 +  0 + lo) * DIM + hi * 32;
  const unsigned char* ga1 = Xq + (size_t)(tileRow + wr * 64 + 16 + lo) * DIM + hi * 32;
  const unsigned char* ga2 = Xq + (size_t)(tileRow + wr * 64 + 32 + lo) * DIM + hi * 32;
  const unsigned char* ga3 = Xq + (size_t)(tileRow + wr * 64 + 48 + lo) * DIM + hi * 32;

  union Frag { i32x4 q[2]; i32x8 v; };

#define STAGE_B(tt, bi) do {                                                           \
    const int kb_ = (tt) * BK;                                                         \
    _Pragma("unroll")                                                                  \
    for (int i_ = 0; i_ < 4; ++i_) {                                                   \
      __builtin_amdgcn_global_load_lds(                                                \
          (const __attribute__((address_space(1))) void*)(gyb + (size_t)i_ * 8 * DIM + kb_), \
          (__attribute__((address_space(3))) void*)&Bs[bi][w * 32 + i_ * 8][0],        \
          16, 0, 0);                                                                   \
    }                                                                                  \
  } while (0)

#define LOAD_A(dst, tt) do {                                                           \
    dst[0].q[0] = *(const i32x4*)(ga0 + (tt) * BK);                                    \
    dst[0].q[1] = *(const i32x4*)(ga0 + (tt) * BK + 16);                               \
    dst[1].q[0] = *(const i32x4*)(ga1 + (tt) * BK);                                    \
    dst[1].q[1] = *(const i32x4*)(ga1 + (tt) * BK + 16);                               \
    dst[2].q[0] = *(const i32x4*)(ga2 + (tt) * BK);                                    \
    dst[2].q[1] = *(const i32x4*)(ga2 + (tt) * BK + 16);                               \
    dst[3].q[0] = *(const i32x4*)(ga3 + (tt) * BK);                                    \
    dst[3].q[1] = *(const i32x4*)(ga3 + (tt) * BK + 16);                               \
  } while (0)

  // one K-step body: compute tile tc from Bs[bi] with frags ac; prefetch
  // A(tn)->an and B(tn)->Bs[bi^1] first (tn = tc+1; skipped when past end)
#define STEP(tc, bi, ac, an) do {                                                      \
    if ((tc) + 1 < KSTEPS) {                                                           \
      STAGE_B((tc) + 1, (bi) ^ 1);                                                     \
      LOAD_A(an, (tc) + 1);                                                            \
    }                                                                                  \
    Frag b[4];                                                                         \
    _Pragma("unroll")                                                                  \
    for (int n_ = 0; n_ < 4; ++n_) {                                                   \
      const unsigned char* r_ = &Bs[bi][wc * 64 + n_ * 16 + lo][0];                    \
      b[n_].q[0] = *(const i32x4*)(r_ + (((hi * 2    ) ^ (lo & 7)) * 16));             \
      b[n_].q[1] = *(const i32x4*)(r_ + (((hi * 2 + 1) ^ (lo & 7)) * 16));             \
    }                                                                                  \
    _Pragma("unroll")                                                                  \
    for (int m_ = 0; m_ < 4; ++m_)                                                     \
      _Pragma("unroll")                                                                \
      for (int n_ = 0; n_ < 4; ++n_)                                                   \
        acc[m_][n_] = __builtin_amdgcn_mfma_scale_f32_16x16x128_f8f6f4(                \
            ac[m_].v, b[n_].v, acc[m_][n_], 0, 0, 0, SCALE_I32, 0, SCALE_I32);         \
    __syncthreads();                                                                   \
  } while (0)

  Frag a0[4], a1[4];

  // prologue: tile 0 (B into buf 0, A into a0)
  STAGE_B(0, 0);
  LOAD_A(a0, 0);
  __syncthreads();   // drains vmcnt(0): B(0) resident; a0 waited by compiler on use

  // main loop, unrolled x2 so a0/a1 are statically indexed (rule #20)
  for (int tt = 0; tt < KSTEPS; tt += 2) {
    STEP(tt,     0, a0, a1);
    STEP(tt + 1, 1, a1, a0);
  }
#undef STEP
#undef LOAD_A
#undef STAGE_B

  // ---- epilogue: exp + per-tile row/col sums ----
  // D layout (16x16 shapes): row = m*16 + hi*4 + q, col = n*16 + lo
  float rp[4][4];
  float cp[4];
#pragma unroll
  for (int m = 0; m < 4; ++m)
#pragma unroll
    for (int q = 0; q < 4; ++q) rp[m][q] = 0.f;
#pragma unroll
  for (int n = 0; n < 4; ++n) cp[n] = 0.f;

#pragma unroll
  for (int m = 0; m < 4; ++m)
#pragma unroll
    for (int n = 0; n < 4; ++n)
#pragma unroll
      for (int q = 0; q < 4; ++q) {
        float e = __expf(acc[m][n][q]);
        rp[m][q] += e;
        cp[n] += e;
      }

#pragma unroll
  for (int m = 0; m < 4; ++m)
#pragma unroll
    for (int q = 0; q < 4; ++q) {
      float v = rp[m][q];
      v += __shfl_xor(v, 1);
      v += __shfl_xor(v, 2);
      v += __shfl_xor(v, 4);
      v += __shfl_xor(v, 8);
      rp[m][q] = v;
    }
#pragma unroll
  for (int n = 0; n < 4; ++n) {
    float v = cp[n];
    v += __shfl_xor(v, 16);
    v += __shfl_xor(v, 32);
    cp[n] = v;
  }

  if (lo == 0) {
#pragma unroll
    for (int m = 0; m < 4; ++m)
#pragma unroll
      for (int q = 0; q < 4; ++q)
        rsum2[wc][wr * 64 + m * 16 + hi * 4 + q] = rp[m][q];
  }
  if (hi == 0) {
#pragma unroll
    for (int n = 0; n < 4; ++n)
      csum2[wr][wc * 64 + n * 16 + lo] = cp[n];
  }
  __syncthreads();

  if (tid < 128) {
    rowpart[(size_t)bn * BSZ + tileRow + tid] = rsum2[0][tid] + rsum2[1][tid];
    colpart[(size_t)bm * BSZ + tileCol + tid] = csum2[0][tid] + csum2[1][tid];
  }
}

// ---------- kernel 3: reduce partials + final expression ----------
__global__ void __launch_bounds__(256) k_final(const float* __restrict__ rowpart,
                                               const float* __restrict__ colpart,
                                               const float* __restrict__ dg,
                                               float* __restrict__ out) {
  const int k = blockIdx.x * 256 + threadIdx.x;
  float rs = 0.f, cs = 0.f;
#pragma unroll 8
  for (int s = 0; s < NTILE; ++s) {
    rs += rowpart[(size_t)s * BSZ + k];
    cs += colpart[(size_t)s * BSZ + k];
  }
  float d = dg[k];
  float p = __expf(d);
  out[k] = logf(cs - p) + logf(rs - p) - 2.0f * d;
}

extern "C" void kernel_launch(void* const* d_in, const int* in_sizes, int n_in,
                              void* d_out, int out_size, void* d_ws, size_t ws_size,
                              hipStream_t stream) {
  const float* X = (const float*)d_in[0];
  const float* Y = (const float*)d_in[1];
  float* out = (float*)d_out;

  char* ws = (char*)d_ws;
  // layout: Xq (16MB) | Yq (16MB) | diag (32KB) | rowpart (2MB) | colpart (2MB)
  unsigned char* Xq = (unsigned char*)ws;
  unsigned char* Yq = (unsigned char*)(ws + (size_t)BSZ * DIM);
  float* diag = (float*)(ws + (size_t)BSZ * DIM * 2);
  float* rowpart = (float*)(ws + (size_t)BSZ * DIM * 2 + BSZ * 4);
  float* colpart = (float*)(ws + (size_t)BSZ * DIM * 2 + BSZ * 4 + (size_t)NTILE * BSZ * 4);

  k_prep<<<BSZ, 256, 0, stream>>>(X, Y, Xq, Yq, diag);
  k_gemm<<<NTILE * NTILE, 256, 0, stream>>>(Xq, Yq, rowpart, colpart);
  k_final<<<BSZ / 256, 256, 0, stream>>>(rowpart, colpart, diag, out);
}

// Round 7
// 134.284 us; speedup vs baseline: 2.2730x; 2.2730x over previous
//
#include <hip/hip_runtime.h>
#include <hip/hip_bf16.h>
#include <math.h>

typedef float f32x4 __attribute__((ext_vector_type(4)));
typedef int   i32x4 __attribute__((ext_vector_type(4)));
typedef int   i32x8 __attribute__((ext_vector_type(8)));

#define BSZ 8192
#define DIM 2048
#define NTILE 64           // 8192 / 128 tiles per side
#define ROWB (DIM / 2)     // fp4 row stride in bytes = 1024
#define BKB 128            // K-step slice per row in BYTES = 256 fp4 elements
#define KSTEPS 8           // 2048 / 256

// MX e8m0 scale byte for 2^-6 (inputs pre-scaled by 64): 127-6 = 121 = 0x79
#define SCALE_I32 0x79797979

// ---------- e2m1 fp4 encode (round to nearest) ----------
// values: 0:0 1:.5 2:1 3:1.5 4:2 5:3 6:4 7:6 ; bit3 = sign
__device__ __forceinline__ unsigned f2fp4(float v) {
  float a = fabsf(v);
  unsigned s = (__float_as_uint(v) >> 31) << 3;
  unsigned m = (a < 0.25f) ? 0u
             : (a < 0.75f) ? 1u
             : (a < 1.25f) ? 2u
             : (a < 1.75f) ? 3u
             : (a < 2.5f)  ? 4u
             : (a < 3.5f)  ? 5u
             : (a < 5.0f)  ? 6u : 7u;
  return s | m;
}

// ---------- kernel 1: fused normalize -> fp4(x*64), diag cos (fp32) ----------
__global__ void __launch_bounds__(256) k_prep(const float* __restrict__ X,
                                              const float* __restrict__ Y,
                                              unsigned char* __restrict__ Xq,
                                              unsigned char* __restrict__ Yq,
                                              float* __restrict__ dg) {
  const int row = blockIdx.x;
  const int tid = threadIdx.x;
  const float4* xp = (const float4*)(X + (size_t)row * DIM);
  const float4* yp = (const float4*)(Y + (size_t)row * DIM);
  float4 x0 = xp[tid * 2], x1 = xp[tid * 2 + 1];
  float4 y0 = yp[tid * 2], y1 = yp[tid * 2 + 1];
  float sxx = x0.x*x0.x + x0.y*x0.y + x0.z*x0.z + x0.w*x0.w
            + x1.x*x1.x + x1.y*x1.y + x1.z*x1.z + x1.w*x1.w;
  float syy = y0.x*y0.x + y0.y*y0.y + y0.z*y0.z + y0.w*y0.w
            + y1.x*y1.x + y1.y*y1.y + y1.z*y1.z + y1.w*y1.w;
  float sxy = x0.x*y0.x + x0.y*y0.y + x0.z*y0.z + x0.w*y0.w
            + x1.x*y1.x + x1.y*y1.y + x1.z*y1.z + x1.w*y1.w;
#pragma unroll
  for (int m = 32; m >= 1; m >>= 1) {
    sxx += __shfl_xor(sxx, m);
    syy += __shfl_xor(syy, m);
    sxy += __shfl_xor(sxy, m);
  }
  __shared__ float sh[3][4];
  if ((tid & 63) == 0) {
    sh[0][tid >> 6] = sxx; sh[1][tid >> 6] = syy; sh[2][tid >> 6] = sxy;
  }
  __syncthreads();
  float xx = sh[0][0] + sh[0][1] + sh[0][2] + sh[0][3];
  float yy = sh[1][0] + sh[1][1] + sh[1][2] + sh[1][3];
  float xy = sh[2][0] + sh[2][1] + sh[2][2] + sh[2][3];
  float nx = fmaxf(sqrtf(xx), 1e-8f);
  float ny = fmaxf(sqrtf(yy), 1e-8f);
  float ix = 64.0f / nx, iy = 64.0f / ny;   // x64 pre-scale onto e2m1 grid
  float vx[8] = {x0.x, x0.y, x0.z, x0.w, x1.x, x1.y, x1.z, x1.w};
  float vy[8] = {y0.x, y0.y, y0.z, y0.w, y1.x, y1.y, y1.z, y1.w};
  unsigned ux = 0, uy = 0;
#pragma unroll
  for (int i = 0; i < 8; ++i) {
    ux |= f2fp4(vx[i] * ix) << (4 * i);
    uy |= f2fp4(vy[i] * iy) << (4 * i);
  }
  *(unsigned*)(Xq + (size_t)row * ROWB + tid * 4) = ux;
  *(unsigned*)(Yq + (size_t)row * ROWB + tid * 4) = uy;
  if (tid == 0) dg[row] = xy / (nx * ny);
}

// ---------- kernel 2: 128x128-tile MX-fp4 (K=256/step) MFMA GEMM ----------
// Round-4 VERIFIED structure: stage via global_load_lds w=16 -> sync ->
// ds_read frags -> mfma_scale -> sync. LDS rows = 128 B = 8 chunks of 16 B;
// XOR-8 swizzle: physical chunk p of row r holds logical chunk p ^ (r&7);
// inverse applied on the global source (rule #21), forward on ds_read.
// fp4: cbsz=blgp=4; each operand frag = 16 B (low 4 VGPRs of the v8i32).
__global__ void __launch_bounds__(256) k_gemm(const unsigned char* __restrict__ Xq,
                                              const unsigned char* __restrict__ Yq,
                                              float* __restrict__ rowpart,
                                              float* __restrict__ colpart) {
  const int bm = blockIdx.x & (NTILE - 1);
  const int bn = blockIdx.x >> 6;
  const int tileRow = bm * 128;
  const int tileCol = bn * 128;

  __shared__ __align__(16) unsigned char As[128][BKB];   // 16 KiB
  __shared__ __align__(16) unsigned char Bs[128][BKB];   // 16 KiB
  __shared__ float rsum2[2][128];
  __shared__ float csum2[2][128];

  const int tid = threadIdx.x;
  const int lane = tid & 63;
  const int w = tid >> 6;        // wave 0..3
  const int wr = w >> 1;         // wave row 0..1  (64-row sub-tile)
  const int wc = w & 1;          // wave col 0..1  (64-col sub-tile)
  const int lo = lane & 15;
  const int hi = lane >> 4;      // k-quarter within one mfma (32 elems = 16 B)

  f32x4 acc[4][4];
#pragma unroll
  for (int m = 0; m < 4; ++m)
#pragma unroll
    for (int n = 0; n < 4; ++n) acc[m][n] = (f32x4){0.f, 0.f, 0.f, 0.f};

  // staging: wave w covers rows [w*32, w*32+32), 8 rows x 128 B per issue.
  // lane l: row +(l>>3), physical chunk l&7 <- logical chunk (l&7)^(l>>3).
  const size_t lrow = (size_t)(lane >> 3);
  const int    lcol = (((lane & 7) ^ (lane >> 3)) * 16);
  const unsigned char* gxa = Xq + ((size_t)(tileRow + w * 32) + lrow) * ROWB + lcol;
  const unsigned char* gyb = Yq + ((size_t)(tileCol + w * 32) + lrow) * ROWB + lcol;

  for (int t = 0; t < KSTEPS; ++t) {
    const int kbase = t * BKB;
#pragma unroll
    for (int i = 0; i < 4; ++i) {
      __builtin_amdgcn_global_load_lds(
          (const __attribute__((address_space(1))) void*)(gxa + (size_t)i * 8 * ROWB + kbase),
          (__attribute__((address_space(3))) void*)&As[w * 32 + i * 8][0],
          16, 0, 0);
      __builtin_amdgcn_global_load_lds(
          (const __attribute__((address_space(1))) void*)(gyb + (size_t)i * 8 * ROWB + kbase),
          (__attribute__((address_space(3))) void*)&Bs[w * 32 + i * 8][0],
          16, 0, 0);
    }
    __syncthreads();

    // two mfma K-halves per step: kk=0 -> logical chunks 0..3, kk=1 -> 4..7.
    // lane's 16 B = k elems (kk*128 + hi*32 .. +31); physical chunk =
    // (kk*4 + hi) ^ (lo&7).
#pragma unroll
    for (int kk = 0; kk < 2; ++kk) {
      i32x4 a[4], b[4];
#pragma unroll
      for (int m = 0; m < 4; ++m)
        a[m] = *(const i32x4*)&As[wr * 64 + m * 16 + lo][((kk * 4 + hi) ^ (lo & 7)) * 16];
#pragma unroll
      for (int n = 0; n < 4; ++n)
        b[n] = *(const i32x4*)&Bs[wc * 64 + n * 16 + lo][((kk * 4 + hi) ^ (lo & 7)) * 16];
#pragma unroll
      for (int m = 0; m < 4; ++m) {
        i32x8 av = {a[m][0], a[m][1], a[m][2], a[m][3], 0, 0, 0, 0};
#pragma unroll
        for (int n = 0; n < 4; ++n) {
          i32x8 bv = {b[n][0], b[n][1], b[n][2], b[n][3], 0, 0, 0, 0};
          acc[m][n] = __builtin_amdgcn_mfma_scale_f32_16x16x128_f8f6f4(
              av, bv, acc[m][n],
              4, 4,                 // cbsz/blgp = FP4 (e2m1)
              0, SCALE_I32,         // scale_a (2^-6)
              0, SCALE_I32);        // scale_b (2^-6)
        }
      }
    }
    __syncthreads();
  }

  // ---- epilogue: exp + per-tile row/col sums ----
  // D layout (16x16 shapes): row = m*16 + hi*4 + q, col = n*16 + lo
  float rp[4][4];
  float cp[4];
#pragma unroll
  for (int m = 0; m < 4; ++m)
#pragma unroll
    for (int q = 0; q < 4; ++q) rp[m][q] = 0.f;
#pragma unroll
  for (int n = 0; n < 4; ++n) cp[n] = 0.f;

#pragma unroll
  for (int m = 0; m < 4; ++m)
#pragma unroll
    for (int n = 0; n < 4; ++n)
#pragma unroll
      for (int q = 0; q < 4; ++q) {
        float e = __expf(acc[m][n][q]);
        rp[m][q] += e;
        cp[n] += e;
      }

#pragma unroll
  for (int m = 0; m < 4; ++m)
#pragma unroll
    for (int q = 0; q < 4; ++q) {
      float v = rp[m][q];
      v += __shfl_xor(v, 1);
      v += __shfl_xor(v, 2);
      v += __shfl_xor(v, 4);
      v += __shfl_xor(v, 8);
      rp[m][q] = v;
    }
#pragma unroll
  for (int n = 0; n < 4; ++n) {
    float v = cp[n];
    v += __shfl_xor(v, 16);
    v += __shfl_xor(v, 32);
    cp[n] = v;
  }

  if (lo == 0) {
#pragma unroll
    for (int m = 0; m < 4; ++m)
#pragma unroll
      for (int q = 0; q < 4; ++q)
        rsum2[wc][wr * 64 + m * 16 + hi * 4 + q] = rp[m][q];
  }
  if (hi == 0) {
#pragma unroll
    for (int n = 0; n < 4; ++n)
      csum2[wr][wc * 64 + n * 16 + lo] = cp[n];
  }
  __syncthreads();

  if (tid < 128) {
    rowpart[(size_t)bn * BSZ + tileRow + tid] = rsum2[0][tid] + rsum2[1][tid];
    colpart[(size_t)bm * BSZ + tileCol + tid] = csum2[0][tid] + csum2[1][tid];
  }
}

// ---------- kernel 3: reduce partials + final expression ----------
__global__ void __launch_bounds__(256) k_final(const float* __restrict__ rowpart,
                                               const float* __restrict__ colpart,
                                               const float* __restrict__ dg,
                                               float* __restrict__ out) {
  const int k = blockIdx.x * 256 + threadIdx.x;
  float rs = 0.f, cs = 0.f;
#pragma unroll 8
  for (int s = 0; s < NTILE; ++s) {
    rs += rowpart[(size_t)s * BSZ + k];
    cs += colpart[(size_t)s * BSZ + k];
  }
  float d = dg[k];
  float p = __expf(d);
  out[k] = logf(cs - p) + logf(rs - p) - 2.0f * d;
}

extern "C" void kernel_launch(void* const* d_in, const int* in_sizes, int n_in,
                              void* d_out, int out_size, void* d_ws, size_t ws_size,
                              hipStream_t stream) {
  const float* X = (const float*)d_in[0];
  const float* Y = (const float*)d_in[1];
  float* out = (float*)d_out;

  char* ws = (char*)d_ws;
  // layout: Xq (8MB) | Yq (8MB) | diag (32KB) | rowpart (2MB) | colpart (2MB)
  unsigned char* Xq = (unsigned char*)ws;
  unsigned char* Yq = (unsigned char*)(ws + (size_t)BSZ * ROWB);
  float* diag = (float*)(ws + (size_t)BSZ * ROWB * 2);
  float* rowpart = (float*)(ws + (size_t)BSZ * ROWB * 2 + BSZ * 4);
  float* colpart = (float*)(ws + (size_t)BSZ * ROWB * 2 + BSZ * 4 + (size_t)NTILE * BSZ * 4);

  k_prep<<<BSZ, 256, 0, stream>>>(X, Y, Xq, Yq, diag);
  k_gemm<<<NTILE * NTILE, 256, 0, stream>>>(Xq, Yq, rowpart, colpart);
  k_final<<<BSZ / 256, 256, 0, stream>>>(rowpart, colpart, diag, out);
}